// Round 3
// baseline (159.251 us; speedup 1.0000x reference)
//
#include <hip/hip_runtime.h>

// 4-qubit circuit, B=2^20, fused single kernel.
// out_w(x) = sum_{a,b in 9x9} K_w[b][a] * F01[a](x0,x1) * F23[b](x2,x3)
// F01/F23: outer products of per-qubit basis {1, cos(pi*x_q), sin(pi*x_q)}.
// K (4x81) depends only on weights; every block recomputes it into LDS:
//   U (phase 1, shuffle-parallel) -> A_w = Re(U^dag Z_w U) (phase 2)
//   -> K via per-qubit basis change (phase 3; validated in round 1).
// Wire w <-> bit (3-w) of flat state index j (wire 0 = MSB).

__global__ __launch_bounds__(512) void qc_fused(const float4* __restrict__ x4,
                                                float4* __restrict__ out4,
                                                const float* __restrict__ w) {
    __shared__ float sUr[16][16], sUi[16][16];   // [j][k]
    __shared__ float sA[4][16][16];              // [w][k][l]
    __shared__ __align__(16) float sK[4 * 9 * 12];  // [w][b][a], rows padded to 12

    const int tid = threadIdx.x;

    // ---- Phase 1: U columns via wave shuffles. thread(k=tid>>4, j=tid&15)
    // holds amplitude j of column k; pair ops are shfl_xor with mask < 16.
    if (tid < 256) {
        const int k = tid >> 4;
        const int j = tid & 15;
        float vr = (j == k) ? 1.f : 0.f;
        float vi = 0.f;
#pragma unroll
        for (int d = 0; d < 2; ++d) {
            // CNOT ring (0,1),(1,2),(2,3),(3,0): v'[j] = (j&mc) ? v[j^mt] : v[j]
#pragma unroll
            for (int p = 0; p < 4; ++p) {
                const int mc = 8 >> p;
                const int mt = 8 >> ((p + 1) & 3);
                const float ur = __shfl_xor(vr, mt);
                const float ui = __shfl_xor(vi, mt);
                if (j & mc) { vr = ur; vi = ui; }
            }
#pragma unroll
            for (int i = 0; i < 4; ++i) {
                const int mw = 8 >> i;
                // RY: j0: v' = c v - s u ; j1: v' = c v + s u   (u = partner)
                const float th = 0.5f * w[(d * 4 + i) * 2 + 0];
                const float c = __cosf(th), s = __sinf(th);
                const float uyr = __shfl_xor(vr, mw);
                const float uyi = __shfl_xor(vi, mw);
                const float sgn = (j & mw) ? s : -s;
                vr = fmaf(sgn, uyr, c * vr);
                vi = fmaf(sgn, uyi, c * vi);
                // RZ: phase (cp, -sp) on bit0, (cp, +sp) on bit1
                const float ph = 0.5f * w[(d * 4 + i) * 2 + 1];
                const float cp = __cosf(ph), sp = __sinf(ph);
                const float pim = (j & mw) ? sp : -sp;
                const float t = cp * vr - pim * vi;
                vi = fmaf(cp, vi, pim * vr);
                vr = t;
            }
        }
        sUr[j][k] = vr;
        sUi[j][k] = vi;
    }
    __syncthreads();

    // ---- Phase 2: A_w[k][l] = sum_j sign_w(j) (Ur[j][k]Ur[j][l]+Ui[j][k]Ui[j][l])
    if (tid < 256) {
        const int k = tid >> 4, l = tid & 15;
        float g[16];
#pragma unroll
        for (int j = 0; j < 16; ++j)
            g[j] = sUr[j][k] * sUr[j][l] + sUi[j][k] * sUi[j][l];
#pragma unroll
        for (int w4 = 0; w4 < 4; ++w4) {
            float a = 0.f;
#pragma unroll
            for (int j = 0; j < 16; ++j)
                a += ((j >> (3 - w4)) & 1) ? -g[j] : g[j];
            sA[w4][k][l] = a;
        }
    }
    __syncthreads();

    // ---- Phase 3: K[w][a][b] = (1/16) sum over 16 pair-choices of +/- A_w[k][l]
    if (tid < 324) {
        const int w4 = tid / 81, r = tid % 81;
        const int bb = r / 9, aa = r % 9;
        const int al[4] = { aa / 3, aa % 3, bb / 3, bb % 3 };
        float acc = 0.f;
#pragma unroll
        for (int t = 0; t < 16; ++t) {
            int k = 0, l = 0;
            float sgn = 1.f;
#pragma unroll
            for (int q = 0; q < 4; ++q) {
                const int alpha = al[q];
                const int c = (t >> q) & 1;
                int bk, bl;
                if (alpha == 2) { bk = c; bl = c ^ 1; }
                else           { bk = c; bl = c; if (alpha == 1 && c) sgn = -sgn; }
                k |= bk << (3 - q);
                l |= bl << (3 - q);
            }
            acc += sgn * sA[w4][k][l];
        }
        sK[(w4 * 9 + bb) * 12 + aa] = acc * 0.0625f;
    }
    __syncthreads();

    // ---- Main: 4 samples per thread; K rows read as uniform ds_read_b128.
    const int base = blockIdx.x * 2048 + tid;
    const float PI = 3.14159265358979323846f;

    float f01[4][8], f23[4][8];   // basis minus the leading 1
#pragma unroll
    for (int s = 0; s < 4; ++s) {
        const float4 xv = x4[base + 512 * s];
        float S0, C0, S1, C1, S2, C2, S3, C3;
        __sincosf(PI * xv.x, &S0, &C0);
        __sincosf(PI * xv.y, &S1, &C1);
        __sincosf(PI * xv.z, &S2, &C2);
        __sincosf(PI * xv.w, &S3, &C3);
        f01[s][0] = C1;       f01[s][1] = S1;
        f01[s][2] = C0;       f01[s][3] = C0 * C1;  f01[s][4] = C0 * S1;
        f01[s][5] = S0;       f01[s][6] = S0 * C1;  f01[s][7] = S0 * S1;
        f23[s][0] = C3;       f23[s][1] = S3;
        f23[s][2] = C2;       f23[s][3] = C2 * C3;  f23[s][4] = C2 * S3;
        f23[s][5] = S2;       f23[s][6] = S2 * C3;  f23[s][7] = S2 * S3;
    }

    float o[4][4];  // [s][w]
#pragma unroll
    for (int W = 0; W < 4; ++W) {
#pragma unroll
        for (int b = 0; b < 9; ++b) {
            const float4 k0 = *reinterpret_cast<const float4*>(&sK[(W * 9 + b) * 12]);
            const float4 k1 = *reinterpret_cast<const float4*>(&sK[(W * 9 + b) * 12 + 4]);
            const float  k8 = sK[(W * 9 + b) * 12 + 8];
#pragma unroll
            for (int s = 0; s < 4; ++s) {
                float tt = k0.x;
                tt = fmaf(k0.y, f01[s][0], tt);
                tt = fmaf(k0.z, f01[s][1], tt);
                tt = fmaf(k0.w, f01[s][2], tt);
                tt = fmaf(k1.x, f01[s][3], tt);
                tt = fmaf(k1.y, f01[s][4], tt);
                tt = fmaf(k1.z, f01[s][5], tt);
                tt = fmaf(k1.w, f01[s][6], tt);
                tt = fmaf(k8,   f01[s][7], tt);
                if (b == 0) o[s][W] = tt;
                else        o[s][W] = fmaf(tt, f23[s][b - 1], o[s][W]);
            }
        }
    }

#pragma unroll
    for (int s = 0; s < 4; ++s)
        out4[base + 512 * s] = make_float4(o[s][0], o[s][1], o[s][2], o[s][3]);
}

extern "C" void kernel_launch(void* const* d_in, const int* in_sizes, int n_in,
                              void* d_out, int out_size, void* d_ws, size_t ws_size,
                              hipStream_t stream) {
    const float* x = (const float*)d_in[0];
    const float* w = (const float*)d_in[1];
    const int B = in_sizes[0] / 4;  // 1,048,576

    hipLaunchKernelGGL(qc_fused, dim3(B / 2048), dim3(512), 0, stream,
                       (const float4*)x, (float4*)d_out, w);
}

// Round 4
// 24.671 us; speedup vs baseline: 6.4550x; 6.4550x over previous
//
#include <hip/hip_runtime.h>

// 4-qubit circuit, B=2^20, two kernels.
// out_w(x) = sum_{a,b in 9x9} K_w[b][a] * F01[a](x0,x1) * F23[b](x2,x3)
// F01/F23: outer products of per-qubit basis {1, cos(pi*x_q), sin(pi*x_q)}.
// K (4x81, padded rows of 12) depends only on weights:
//   U (shuffle-parallel) -> A_w = Re(U^dag Z_w U) -> K (validated R1/R2).
// Wire w <-> bit (3-w) of flat state index j (wire 0 = MSB).

__device__ __align__(16) float g_K[4 * 9 * 12];  // [w][b][a], rows padded to 12

// ---------------- prep: weights -> g_K (one block, shuffle-parallel) ----------
__global__ __launch_bounds__(384) void qc_prep(const float* __restrict__ w) {
    __shared__ float sUr[16][16], sUi[16][16];   // [j][k]
    __shared__ float sA[4][16][16];              // [w][k][l]
    const int tid = threadIdx.x;

    // Phase 1: thread(k=tid>>4, j=tid&15) holds amplitude j of U column k.
    if (tid < 256) {
        const int k = tid >> 4;
        const int j = tid & 15;
        float vr = (j == k) ? 1.f : 0.f;
        float vi = 0.f;
#pragma unroll
        for (int d = 0; d < 2; ++d) {
#pragma unroll
            for (int p = 0; p < 4; ++p) {           // CNOT ring
                const int mc = 8 >> p;
                const int mt = 8 >> ((p + 1) & 3);
                const float ur = __shfl_xor(vr, mt);
                const float ui = __shfl_xor(vi, mt);
                if (j & mc) { vr = ur; vi = ui; }
            }
#pragma unroll
            for (int i = 0; i < 4; ++i) {
                const int mw = 8 >> i;
                const float th = 0.5f * w[(d * 4 + i) * 2 + 0];
                const float c = __cosf(th), s = __sinf(th);
                const float uyr = __shfl_xor(vr, mw);
                const float uyi = __shfl_xor(vi, mw);
                const float sgn = (j & mw) ? s : -s;
                vr = fmaf(sgn, uyr, c * vr);
                vi = fmaf(sgn, uyi, c * vi);
                const float ph = 0.5f * w[(d * 4 + i) * 2 + 1];
                const float cp = __cosf(ph), sp = __sinf(ph);
                const float pim = (j & mw) ? sp : -sp;
                const float t = cp * vr - pim * vi;
                vi = fmaf(cp, vi, pim * vr);
                vr = t;
            }
        }
        sUr[j][k] = vr;
        sUi[j][k] = vi;
    }
    __syncthreads();

    // Phase 2: A_w[k][l] = sum_j sign_w(j) (Ur[j][k]Ur[j][l]+Ui[j][k]Ui[j][l])
    if (tid < 256) {
        const int k = tid >> 4, l = tid & 15;
        float g[16];
#pragma unroll
        for (int j = 0; j < 16; ++j)
            g[j] = sUr[j][k] * sUr[j][l] + sUi[j][k] * sUi[j][l];
#pragma unroll
        for (int w4 = 0; w4 < 4; ++w4) {
            float a = 0.f;
#pragma unroll
            for (int j = 0; j < 16; ++j)
                a += ((j >> (3 - w4)) & 1) ? -g[j] : g[j];
            sA[w4][k][l] = a;
        }
    }
    __syncthreads();

    // Phase 3: K[w][a][b] = (1/16) sum over 16 pair-choices of +/- A_w[k][l]
    if (tid < 324) {
        const int w4 = tid / 81, r = tid % 81;
        const int bb = r / 9, aa = r % 9;
        const int al[4] = { aa / 3, aa % 3, bb / 3, bb % 3 };
        float acc = 0.f;
#pragma unroll
        for (int t = 0; t < 16; ++t) {
            int k = 0, l = 0;
            float sgn = 1.f;
#pragma unroll
            for (int q = 0; q < 4; ++q) {
                const int alpha = al[q];
                const int c = (t >> q) & 1;
                int bk, bl;
                if (alpha == 2) { bk = c; bl = c ^ 1; }
                else           { bk = c; bl = c; if (alpha == 1 && c) sgn = -sgn; }
                k |= bk << (3 - q);
                l |= bl << (3 - q);
            }
            acc += sgn * sA[w4][k][l];
        }
        g_K[(w4 * 9 + bb) * 12 + aa] = acc * 0.0625f;
    }
}

// ---------------- main: 4 samples/thread; K rows = uniform float4 loads -------
__global__ __launch_bounds__(256, 2) void qc_main(const float4* __restrict__ x4,
                                                  float4* __restrict__ out4) {
    const int base = blockIdx.x * 1024 + threadIdx.x;
    const float PI = 3.14159265358979323846f;

    float f01[4][8], f23[4][8];   // basis minus the leading 1
#pragma unroll
    for (int s = 0; s < 4; ++s) {
        const float4 xv = x4[base + 256 * s];
        float S0, C0, S1, C1, S2, C2, S3, C3;
        __sincosf(PI * xv.x, &S0, &C0);
        __sincosf(PI * xv.y, &S1, &C1);
        __sincosf(PI * xv.z, &S2, &C2);
        __sincosf(PI * xv.w, &S3, &C3);
        f01[s][0] = C1;       f01[s][1] = S1;
        f01[s][2] = C0;       f01[s][3] = C0 * C1;  f01[s][4] = C0 * S1;
        f01[s][5] = S0;       f01[s][6] = S0 * C1;  f01[s][7] = S0 * S1;
        f23[s][0] = C3;       f23[s][1] = S3;
        f23[s][2] = C2;       f23[s][3] = C2 * C3;  f23[s][4] = C2 * S3;
        f23[s][5] = S2;       f23[s][6] = S2 * C3;  f23[s][7] = S2 * S3;
    }

    float o[4][4];  // [s][w]
#pragma unroll
    for (int W = 0; W < 4; ++W) {
#pragma unroll
        for (int b = 0; b < 9; ++b) {
            const float* Kr = g_K + (W * 9 + b) * 12;
            const float4 k0 = *reinterpret_cast<const float4*>(Kr);
            const float4 k1 = *reinterpret_cast<const float4*>(Kr + 4);
            const float  k8 = Kr[8];
#pragma unroll
            for (int s = 0; s < 4; ++s) {
                float tt = k0.x;
                tt = fmaf(k0.y, f01[s][0], tt);
                tt = fmaf(k0.z, f01[s][1], tt);
                tt = fmaf(k0.w, f01[s][2], tt);
                tt = fmaf(k1.x, f01[s][3], tt);
                tt = fmaf(k1.y, f01[s][4], tt);
                tt = fmaf(k1.z, f01[s][5], tt);
                tt = fmaf(k1.w, f01[s][6], tt);
                tt = fmaf(k8,   f01[s][7], tt);
                if (b == 0) o[s][W] = tt;
                else        o[s][W] = fmaf(tt, f23[s][b - 1], o[s][W]);
            }
        }
    }

#pragma unroll
    for (int s = 0; s < 4; ++s)
        out4[base + 256 * s] = make_float4(o[s][0], o[s][1], o[s][2], o[s][3]);
}

extern "C" void kernel_launch(void* const* d_in, const int* in_sizes, int n_in,
                              void* d_out, int out_size, void* d_ws, size_t ws_size,
                              hipStream_t stream) {
    const float* x = (const float*)d_in[0];
    const float* w = (const float*)d_in[1];
    const int B = in_sizes[0] / 4;  // 1,048,576

    hipLaunchKernelGGL(qc_prep, dim3(1), dim3(384), 0, stream, w);
    hipLaunchKernelGGL(qc_main, dim3(B / 1024), dim3(256), 0, stream,
                       (const float4*)x, (float4*)d_out);
}